// Round 9
// baseline (241.294 us; speedup 1.0000x reference)
//
#include <hip/hip_runtime.h>
#include <hip/hip_bf16.h>

#define TPB   64
#define GRID  1024
#define BUFSZ 8192   // one table-batch: 64 rows x 128 B

typedef float f2 __attribute__((ext_vector_type(2)));
typedef __attribute__((address_space(3))) char* lds_ptr_t;

#define MEMBAR    asm volatile("" ::: "memory")
#define WAITVM(K) asm volatile("s_waitcnt vmcnt(" K ")" ::: "memory")

// ws layout (fp32): W[grp*256 + j*32 + k] = w1[j][grp*32+k], grp 0:u*m 1:u 2:m
// W[768+j]=b1[j]; W[776+j]=w2[j]; W[784]=b2
__global__ void prep_kernel(const float* __restrict__ w1, const float* __restrict__ b1,
                            const float* __restrict__ w2, const float* __restrict__ b2,
                            float* __restrict__ W) {
    int t = threadIdx.x;
    for (int i = t; i < 768; i += TPB) {
        int grp = i >> 8, r = i & 255, j = r >> 5, k = r & 31;
        W[i] = w1[j * 96 + grp * 32 + k];
    }
    if (t < 8) W[768 + t] = b1[t];
    if (t < 8) W[776 + t] = w2[t];
    if (t == 0) W[784]    = b2[0];
}

// Compute one batch from LDS buffers at byte-offsets ub/mb (per-thread row base).
// All 16 ds_read_b128 + the lgkmcnt wait in ONE asm block. Outputs are
// EARLY-CLOBBER ("=&v"): the first read writes its dest while later reads
// still need their address inputs — without & the allocator may alias them
// (round 8's absmax 3.9e-2 bug). Hidden from the compiler's LDS-DMA
// legalizer so no auto vmcnt(0) drain is inserted.
__device__ __forceinline__ void compute_store(
    unsigned ub, unsigned mb, int xs, const float* __restrict__ W,
    float* __restrict__ out, int g, int n, int l) {
    unsigned au[8], am[8];
#pragma unroll
    for (int q = 0; q < 8; ++q) {
        unsigned off = (unsigned)(xs ^ (q << 4));   // position q^x holds chunk q
        au[q] = ub + off;
        am[q] = mb + off;
    }
    float4 u[8], m[8];
    asm volatile(
        "ds_read_b128 %0, %16\n\t"
        "ds_read_b128 %1, %17\n\t"
        "ds_read_b128 %2, %18\n\t"
        "ds_read_b128 %3, %19\n\t"
        "ds_read_b128 %4, %20\n\t"
        "ds_read_b128 %5, %21\n\t"
        "ds_read_b128 %6, %22\n\t"
        "ds_read_b128 %7, %23\n\t"
        "ds_read_b128 %8, %24\n\t"
        "ds_read_b128 %9, %25\n\t"
        "ds_read_b128 %10, %26\n\t"
        "ds_read_b128 %11, %27\n\t"
        "ds_read_b128 %12, %28\n\t"
        "ds_read_b128 %13, %29\n\t"
        "ds_read_b128 %14, %30\n\t"
        "ds_read_b128 %15, %31\n\t"
        "s_waitcnt lgkmcnt(0)"
        : "=&v"(u[0]), "=&v"(u[1]), "=&v"(u[2]), "=&v"(u[3]),
          "=&v"(u[4]), "=&v"(u[5]), "=&v"(u[6]), "=&v"(u[7]),
          "=&v"(m[0]), "=&v"(m[1]), "=&v"(m[2]), "=&v"(m[3]),
          "=&v"(m[4]), "=&v"(m[5]), "=&v"(m[6]), "=&v"(m[7])
        : "v"(au[0]), "v"(au[1]), "v"(au[2]), "v"(au[3]),
          "v"(au[4]), "v"(au[5]), "v"(au[6]), "v"(au[7]),
          "v"(am[0]), "v"(am[1]), "v"(am[2]), "v"(am[3]),
          "v"(am[4]), "v"(am[5]), "v"(am[6]), "v"(am[7])
        : "memory");

    const f2* Wp = (const f2*)W;   // pair index = grp*128 + j*16 + d
    f2 h2[8];
#pragma unroll
    for (int j = 0; j < 8; ++j) { h2[j].x = W[768 + j]; h2[j].y = 0.0f; }
#pragma unroll
    for (int q = 0; q < 8; ++q) {
        f2 u0, u1, m0, m1;
        u0.x = u[q].x; u0.y = u[q].y;  u1.x = u[q].z; u1.y = u[q].w;
        m0.x = m[q].x; m0.y = m[q].y;  m1.x = m[q].z; m1.y = m[q].w;
        f2 p0 = u0 * m0;
        f2 p1 = u1 * m1;
        int d0 = 2 * q, d1 = 2 * q + 1;
#pragma unroll
        for (int j = 0; j < 8; ++j) {
            h2[j] = __builtin_elementwise_fma(p0, Wp[      j * 16 + d0], h2[j]);
            h2[j] = __builtin_elementwise_fma(u0, Wp[128 + j * 16 + d0], h2[j]);
            h2[j] = __builtin_elementwise_fma(m0, Wp[256 + j * 16 + d0], h2[j]);
            h2[j] = __builtin_elementwise_fma(p1, Wp[      j * 16 + d1], h2[j]);
            h2[j] = __builtin_elementwise_fma(u1, Wp[128 + j * 16 + d1], h2[j]);
            h2[j] = __builtin_elementwise_fma(m1, Wp[256 + j * 16 + d1], h2[j]);
        }
    }
    float z = W[784];
#pragma unroll
    for (int j = 0; j < 8; ++j) {
        float hj = h2[j].x + h2[j].y;
        z = fmaf(fmaxf(hj, 0.0f), W[776 + j], z);
    }
    float r = 1.0f / (1.0f + __expf(-z));
    int e0 = g * 64 + l;
    if (e0 < n) out[e0] = r;
}

__global__ __launch_bounds__(TPB) void mf_kernel(
    const int* __restrict__ users, const int* __restrict__ movies,
    const char* __restrict__ uemb,   // fp32 [1e6][32] = 128 B rows
    const char* __restrict__ memb,   // fp32 [1e5][32]
    const float* __restrict__ W,
    float* __restrict__ out, int n) {
    __shared__ __align__(16) char lds[5 * BUFSZ];   // 40960 B -> 4 blocks/CU

    const int l    = threadIdx.x;
    const int slot = l >> 3;          // row this lane serves per gather instr
    const int pos  = l & 7;           // 16 B position this lane writes (HW lane-linear)
    const int cg   = pos ^ slot;      // chunk fetched: write-side swizzle for read banks
    const int xs   = (l & 7) << 4;
    const int b0   = (int)blockIdx.x;
    const int tb   = (n + 63) >> 6;   // total batches of 64
    int nb = (tb - b0 + GRID - 1) / GRID;
    if (nb <= 0) return;

    lds_ptr_t lb = (lds_ptr_t)&lds[0];
    unsigned lbu = (unsigned)(unsigned long long)lb;
    unsigned rowb = lbu + (unsigned)(l >> 3) * 1024u + (unsigned)(l & 7) * 128u;

    // Per-lane row-index loads for a batch: lane l serves row of element 8s+slot.
#define LOAD_GEN(g, RU, RM) do {                                   \
        int _g = (g);                                              \
        _Pragma("unroll")                                          \
        for (int s = 0; s < 8; ++s) {                              \
            int _e = _g * 64 + 8 * s + slot;                       \
            if (_e >= n) _e = n - 1;                               \
            (RU)[s] = users[_e];                                   \
            (RM)[s] = movies[_e];                                  \
        }                                                          \
    } while (0)

#define GATHER8(tbl, R, bufidx) do {                                            \
        lds_ptr_t _d = lb + (bufidx) * BUFSZ;                                   \
        _Pragma("unroll")                                                       \
        for (int s = 0; s < 8; ++s) {                                           \
            __builtin_amdgcn_global_load_lds(                                   \
                (const __attribute__((address_space(1))) void*)                 \
                    ((tbl) + (size_t)(R)[s] * 128 + (size_t)(cg * 16)),         \
                (__attribute__((address_space(3))) void*)(_d + s * 1024),       \
                16, 0, 0);                                                      \
        }                                                                       \
    } while (0)

    int ruc[8], rmc[8], run[8], rmn[8];

    // ---- prologue: gens 0,1,2 + gathers for batches 0,1 (48 VM ops in flight) ----
    LOAD_GEN(b0, ruc, rmc);            MEMBAR;   // gen0 (16)
    LOAD_GEN(b0 + GRID, run, rmn);     MEMBAR;   // gen1 (16)
    WAITVM("16");                                // gen0 done
    GATHER8(uemb, ruc, 0);                       // U0 -> buf0
    GATHER8(memb, rmc, 1);             MEMBAR;   // M0 -> buf1
    LOAD_GEN(b0 + 2 * GRID, ruc, rmc); MEMBAR;   // gen2 (16) into cur
    WAITVM("32");                                // gen1 done (newer: U0,M0,gen2)
    GATHER8(uemb, run, 2);                       // U1 -> buf2
    GATHER8(memb, rmn, 3);             MEMBAR;   // M1 -> buf3

    int bu = 0;   // batch i: U in buf (2i)%5, M in (2i+1)%5

#define PIPE_ITER(i, K) do {                                                    \
        WAITVM(K);                                                              \
        LOAD_GEN(b0 + ((i) + 3) * GRID, run, rmn);  MEMBAR;                     \
        int _wu = bu + 4; if (_wu >= 5) _wu -= 5;                               \
        GATHER8(uemb, ruc, _wu);                    MEMBAR;                     \
        int _bm = bu + 1; if (_bm >= 5) _bm = 0;                                \
        compute_store(rowb + (unsigned)bu * BUFSZ, rowb + (unsigned)_bm * BUFSZ,\
                      xs, W, out, b0 + (i) * GRID, n, l);           MEMBAR;     \
        GATHER8(memb, rmc, bu);                     MEMBAR;                     \
        _Pragma("unroll")                                                       \
        for (int s = 0; s < 8; ++s) { ruc[s] = run[s]; rmc[s] = rmn[s]; }       \
        bu += 2; if (bu >= 5) bu -= 5;                                          \
    } while (0)

    if (nb >= 3) {
        PIPE_ITER(0, "16");                       // retire U0,M0,gen2
        for (int i = 1; i + 3 <= nb; ++i) {
            PIPE_ITER(i, "17");                   // steady: keep next batch in flight
        }
    }

    // ---- epilogue: drain, compute the last 1-2 batches ----
    WAITVM("0");
    int done = (nb >= 3) ? nb - 2 : 0;
    for (int i = done; i < nb; ++i) {
        int bue = (2 * i) % 5;
        int bme = (2 * i + 1) % 5;
        compute_store(rowb + (unsigned)bue * BUFSZ, rowb + (unsigned)bme * BUFSZ,
                      xs, W, out, b0 + i * GRID, n, l);
    }
#undef PIPE_ITER
#undef GATHER8
#undef LOAD_GEN
}

extern "C" void kernel_launch(void* const* d_in, const int* in_sizes, int n_in,
                              void* d_out, int out_size, void* d_ws, size_t ws_size,
                              hipStream_t stream) {
    const int* users  = (const int*)d_in[0];
    const int* movies = (const int*)d_in[1];
    const char* uemb  = (const char*)d_in[2];    // fp32 [1e6, 32]
    const char* memb  = (const char*)d_in[3];    // fp32 [1e5, 32]
    const float* w1   = (const float*)d_in[4];   // fp32 [8, 96]
    const float* b1   = (const float*)d_in[5];   // fp32 [8]
    const float* w2   = (const float*)d_in[6];   // fp32 [1, 8]
    const float* b2   = (const float*)d_in[7];   // fp32 [1]
    float* ws  = (float*)d_ws;
    float* out = (float*)d_out;

    int n = in_sizes[0];

    prep_kernel<<<1, TPB, 0, stream>>>(w1, b1, w2, b2, ws);
    mf_kernel<<<GRID, TPB, 0, stream>>>(users, movies, uemb, memb, ws, out, n);
}